// Round 5
// baseline (719.496 us; speedup 1.0000x reference)
//
#include <hip/hip_runtime.h>
#include <hip/hip_cooperative_groups.h>

namespace cg = cooperative_groups;

// Problem constants (from reference setup_inputs)
#define B_   16
#define C_   64
#define HW_  65536   // 256*256
#define GB   8       // batches per group (128 MiB working set, L3 = 256 MiB)
#define NG   (B_ / GB)
#define NBLK 1024    // 4 blocks/CU x 256 CUs
#define NTHR 256
#define TILE 64      // pixels per tile in persistent fused phase (LDS 16 KiB)
#define TILE2 128    // fallback fused kernel tile

typedef float f4_t __attribute__((ext_vector_type(4)));

// fast branch-free tanh: 1 - 2/(e^2z + 1), clamped
__device__ __forceinline__ float fast_tanh(float z) {
    z = fminf(fmaxf(z, -15.f), 15.f);
    float e = __expf(2.f * z);
    return 1.f - 2.f * __builtin_amdgcn_rcpf(e + 1.f);
}

// ---------------------------------------------------------------------------
// Persistent cooperative kernel. Per group of GB batches:
//   A: 1024 half-channel reductions (one per block) -> part[]
//   threadfence + grid.sync()
//   B: every block redundantly computes the tiny GCN math for the group's
//      GB batches into LDS (identical FP ops -> identical values everywhere)
//   C: fused y + phi + tanh; x reads should be L3-hot from phase A.
// Groups touch disjoint part[] regions -> one grid sync per group.
// LDS ~23 KiB -> 4 blocks/CU uses 92 KiB of 160 KiB (safe coop occupancy).
// ---------------------------------------------------------------------------
__global__ __launch_bounds__(NTHR, 4) void k_all(
    const float* __restrict__ x,
    const float* __restrict__ theta_w, const float* __restrict__ theta_b,
    const float* __restrict__ g1_w,    const float* __restrict__ g1_b,
    const float* __restrict__ g2_w,    const float* __restrict__ g2_b,
    const float* __restrict__ phi_w,   const float* __restrict__ phi_b,
    float* __restrict__ part, float* __restrict__ out) {

    __shared__ float tile[C_][TILE];      // 16 KiB
    __shared__ float ys[TILE];
    __shared__ float pw[C_], pb[C_];
    __shared__ float xn_all[GB][C_];
    __shared__ float z1_all[GB][C_];
    __shared__ float wsh_all[GB][C_];
    __shared__ float bias_all[GB];
    __shared__ float ls[4];

    cg::grid_group grid = cg::this_grid();
    int t = threadIdx.x;

    if (t < C_) { pw[t] = phi_w[t]; pb[t] = phi_b[t]; }
    float g2w0 = g2_w[0], g2b0 = g2_b[0];

    for (int g = 0; g < NG; ++g) {
        int b0 = g * GB;

        // ---------------- Phase A: half-channel reductions ----------------
        {
            int task = blockIdx.x;              // 0..1023
            int half = task & 1;
            int bcl  = task >> 1;               // bi*64 + c
            int bc   = (b0 + (bcl >> 6)) * C_ + (bcl & 63);
            const float4* p4 =
                (const float4*)(x + (size_t)bc * HW_ + half * (HW_ / 2));
            float s = 0.f;
#pragma unroll
            for (int i = 0; i < 32; ++i) {
                float4 v = p4[t + 256 * i];
                s += (v.x + v.y) + (v.z + v.w);
            }
#pragma unroll
            for (int off = 32; off; off >>= 1) s += __shfl_down(s, off, 64);
            __syncthreads();                    // ls reuse guard
            if ((t & 63) == 0) ls[t >> 6] = s;
            __syncthreads();
            if (t == 0) part[bc * 2 + half] = (ls[0] + ls[1]) + (ls[2] + ls[3]);
        }

        __threadfence();                        // make part[] device-visible
        grid.sync();

        // -------- Phase B: redundant per-block tiny GCN math (GB batches) --
#pragma unroll
        for (int k = 0; k < 2; ++k) {
            int idx = k * NTHR + t;             // 0..511
            int bi = idx >> 6, c = idx & 63;
            int bg = b0 + bi;
            float pa = part[(bg * C_ + c) * 2];
            float pv = part[(bg * C_ + c) * 2 + 1];
            xn_all[bi][c] = (pa + pv) * (1.0f / (float)HW_);
        }
        __syncthreads();
#pragma unroll
        for (int k = 0; k < 2; ++k) {
            int idx = k * NTHR + t;
            int bi = idx >> 6, n = idx & 63;
            float h = g1_b[n];
#pragma unroll
            for (int c = 0; c < C_; ++c) h += xn_all[bi][c] * g1_w[n * C_ + c];
            z1_all[bi][n] = h * g2w0 + g2b0;
        }
        __syncthreads();
#pragma unroll
        for (int k = 0; k < 2; ++k) {
            int idx = k * NTHR + t;
            int bi = idx >> 6, c = idx & 63;
            float w = 0.f;
#pragma unroll
            for (int n = 0; n < C_; ++n) w += z1_all[bi][n] * theta_w[n * C_ + c];
            wsh_all[bi][c] = w;
            if (c == 0) {
                float bb = 0.f;
#pragma unroll
                for (int n = 0; n < C_; ++n) bb += z1_all[bi][n] * theta_b[n];
                bias_all[bi] = bb;
            }
        }
        __syncthreads();

        // ---------------- Phase C: fused out, 8 tiles per block -----------
        for (int rep = 0; rep < (GB * (HW_ / TILE)) / NBLK; ++rep) {
            int tid_ = rep * NBLK + blockIdx.x;   // 0..8191
            int bi = tid_ >> 10;                  // HW/TILE = 1024 tiles/batch
            int b  = b0 + bi;
            int p0 = (tid_ & 1023) * TILE;

            const float* xb = x + (size_t)b * C_ * HW_ + p0;
#pragma unroll
            for (int i = 0; i < 4; ++i) {
                int f = i * NTHR + t, c = f >> 4, j = f & 15;  // 16 f4/row
                *(float4*)&tile[c][4 * j] =
                    *(const float4*)(xb + (size_t)c * HW_ + 4 * j);
            }
            __syncthreads();
            if (t < TILE) {
                float y = bias_all[bi];
#pragma unroll
                for (int c = 0; c < C_; ++c) y += wsh_all[bi][c] * tile[c][t];
                ys[t] = y;
            }
            __syncthreads();
            float* ob = out + (size_t)b * C_ * HW_ + p0;
#pragma unroll
            for (int i = 0; i < 4; ++i) {
                int f = i * NTHR + t, c = f >> 4, j = f & 15;
                float4 v  = *(float4*)&tile[c][4 * j];
                float4 yv = *(float4*)&ys[4 * j];
                float a = pw[c], d = pb[c];
                f4_t r;
                r.x = fast_tanh(yv.x * a + d + v.x);
                r.y = fast_tanh(yv.y * a + d + v.y);
                r.z = fast_tanh(yv.z * a + d + v.z);
                r.w = fast_tanh(yv.w * a + d + v.w);
                __builtin_nontemporal_store(r, (f4_t*)(ob + (size_t)c * HW_ + 4 * j));
            }
            __syncthreads();                      // tile reuse guard
        }
    }
}

// ===========================================================================
// Fallback path (round-2 structure) -- used only if cooperative launch fails.
// ===========================================================================
__global__ __launch_bounds__(256) void k_reduce_mean(
    const float* __restrict__ x, float* __restrict__ x_node) {
    int bc  = blockIdx.x;
    int tid = threadIdx.x;
    const float4* p4 = (const float4*)(x + (size_t)bc * HW_);
    float s = 0.f;
#pragma unroll
    for (int i = 0; i < 64; ++i) {
        float4 v = p4[tid + 256 * i];
        s += (v.x + v.y) + (v.z + v.w);
    }
#pragma unroll
    for (int off = 32; off; off >>= 1) s += __shfl_down(s, off, 64);
    __shared__ float ls[4];
    int wid = tid >> 6, lane = tid & 63;
    if (lane == 0) ls[wid] = s;
    __syncthreads();
    if (tid == 0) x_node[bc] = ((ls[0] + ls[1]) + (ls[2] + ls[3])) * (1.0f / (float)HW_);
}

__global__ __launch_bounds__(1024) void k_small(
    const float* __restrict__ x_node,
    const float* __restrict__ theta_w, const float* __restrict__ theta_b,
    const float* __restrict__ g1_w,    const float* __restrict__ g1_b,
    const float* __restrict__ g2_w,    const float* __restrict__ g2_b,
    float* __restrict__ w_eff, float* __restrict__ bias_eff) {
    int t = threadIdx.x;
    int b = t >> 6, n = t & 63;
    __shared__ float z1s[B_][C_];
    float h = g1_b[n];
#pragma unroll
    for (int c = 0; c < C_; ++c) h += x_node[b * C_ + c] * g1_w[n * C_ + c];
    z1s[b][n] = h * g2_w[0] + g2_b[0];
    __syncthreads();
    int c = n;
    float w = 0.f;
#pragma unroll
    for (int nn = 0; nn < C_; ++nn) w += z1s[b][nn] * theta_w[nn * C_ + c];
    w_eff[b * C_ + c] = w;
    if (c == 0) {
        float bb = 0.f;
#pragma unroll
        for (int nn = 0; nn < C_; ++nn) bb += z1s[b][nn] * theta_b[nn];
        bias_eff[b] = bb;
    }
}

__global__ __launch_bounds__(256) void k_fused_out(
    const float* __restrict__ x,
    const float* __restrict__ w_eff, const float* __restrict__ bias_eff,
    const float* __restrict__ phi_w, const float* __restrict__ phi_b,
    float* __restrict__ out) {
    __shared__ float tile[C_][TILE2];
    __shared__ float ys[TILE2];
    __shared__ float wsh[C_], pw[C_], pb[C_];
    int t  = threadIdx.x;
    int b  = blockIdx.x >> 9;
    int ti = blockIdx.x & 511;
    int p0 = ti * TILE2;
    if (t < C_) { wsh[t] = w_eff[b * C_ + t]; pw[t] = phi_w[t]; pb[t] = phi_b[t]; }
    const float* xb = x + (size_t)b * C_ * HW_ + p0;
#pragma unroll
    for (int i = 0; i < 8; ++i) {
        int f = i * 256 + t, c = f >> 5, j = f & 31;
        *(float4*)&tile[c][4 * j] = *(const float4*)(xb + (size_t)c * HW_ + 4 * j);
    }
    __syncthreads();
    if (t < TILE2) {
        float y = bias_eff[b];
#pragma unroll
        for (int c = 0; c < C_; ++c) y += wsh[c] * tile[c][t];
        ys[t] = y;
    }
    __syncthreads();
    float* ob = out + (size_t)b * C_ * HW_ + p0;
#pragma unroll
    for (int i = 0; i < 8; ++i) {
        int f = i * 256 + t, c = f >> 5, j = f & 31;
        float4 v  = *(float4*)&tile[c][4 * j];
        float4 yv = *(float4*)&ys[4 * j];
        float a = pw[c], d = pb[c];
        f4_t r;
        r.x = fast_tanh(yv.x * a + d + v.x);
        r.y = fast_tanh(yv.y * a + d + v.y);
        r.z = fast_tanh(yv.z * a + d + v.z);
        r.w = fast_tanh(yv.w * a + d + v.w);
        __builtin_nontemporal_store(r, (f4_t*)(ob + (size_t)c * HW_ + 4 * j));
    }
}

// ---------------------------------------------------------------------------
extern "C" void kernel_launch(void* const* d_in, const int* in_sizes, int n_in,
                              void* d_out, int out_size, void* d_ws, size_t ws_size,
                              hipStream_t stream) {
    const float* x       = (const float*)d_in[0];
    const float* theta_w = (const float*)d_in[1];
    const float* theta_b = (const float*)d_in[2];
    const float* g1_w    = (const float*)d_in[3];
    const float* g1_b    = (const float*)d_in[4];
    const float* g2_w    = (const float*)d_in[5];
    const float* g2_b    = (const float*)d_in[6];
    const float* phi_w   = (const float*)d_in[7];
    const float* phi_b   = (const float*)d_in[8];
    float* out = (float*)d_out;

    float* part     = (float*)d_ws;                 // B*C*2 floats
    float* x_node   = part + B_ * C_ * 2;           // B*C floats (fallback)
    float* w_eff    = x_node + B_ * C_;             // B*C floats (fallback)
    float* bias_eff = w_eff + B_ * C_;              // B floats   (fallback)

    void* args[] = {
        (void*)&x, (void*)&theta_w, (void*)&theta_b,
        (void*)&g1_w, (void*)&g1_b, (void*)&g2_w, (void*)&g2_b,
        (void*)&phi_w, (void*)&phi_b, (void*)&part, (void*)&out
    };
    hipError_t err = hipLaunchCooperativeKernel((void*)k_all, dim3(NBLK),
                                                dim3(NTHR), args, 0, stream);
    if (err != hipSuccess) {
        // deterministic fallback: known-good 3-kernel path
        k_reduce_mean<<<B_ * C_, 256, 0, stream>>>(x, x_node);
        k_small<<<1, B_ * C_, 0, stream>>>(x_node, theta_w, theta_b, g1_w, g1_b,
                                           g2_w, g2_b, w_eff, bias_eff);
        k_fused_out<<<B_ * (HW_ / TILE2), 256, 0, stream>>>(
            x, w_eff, bias_eff, phi_w, phi_b, out);
    }
}

// Round 6
// 201.267 us; speedup vs baseline: 3.5748x; 3.5748x over previous
//
#include <hip/hip_runtime.h>
#include <hip/hip_bf16.h>

// Problem constants (from reference setup_inputs)
#define B_   16
#define C_   64
#define HW_  65536   // 256*256
#define TILE 128     // pixels per block in fused kernel

typedef float f4_t __attribute__((ext_vector_type(4)));

// fast branch-free tanh: 1 - 2/(e^2z + 1), clamped
__device__ __forceinline__ float fast_tanh(float z) {
    z = fminf(fmaxf(z, -15.f), 15.f);
    float e = __expf(2.f * z);
    return 1.f - 2.f * __builtin_amdgcn_rcpf(e + 1.f);
}

// ---------------------------------------------------------------------------
// Kernel 1: half-channel reductions over all B batches; the last-finishing
// block of each batch (device-scope atomic counter, 128 blocks/batch) also
// computes the tiny GCN math -> w_eff[b,:], bias_eff[b]. Values are
// deterministic regardless of which block finishes last.
// grid = B*C*2 = 2048 blocks, 256 threads.
// ---------------------------------------------------------------------------
__global__ __launch_bounds__(256) void k_reduce_gcn(
    const float* __restrict__ x,
    const float* __restrict__ theta_w, const float* __restrict__ theta_b,
    const float* __restrict__ g1_w,    const float* __restrict__ g1_b,
    const float* __restrict__ g2_w,    const float* __restrict__ g2_b,
    float* __restrict__ part, float* __restrict__ w_eff,
    float* __restrict__ bias_eff, int* __restrict__ cnt) {
    int t    = threadIdx.x;
    int blk  = blockIdx.x;          // 0..2047
    int half = blk & 1;
    int bcl  = blk >> 1;            // 0..1023 : b*64 + c
    int b    = bcl >> 6;
    int c    = bcl & 63;
    int bc   = b * C_ + c;

    const float4* p4 = (const float4*)(x + (size_t)bc * HW_ + half * (HW_ / 2));
    float s = 0.f;
#pragma unroll
    for (int i = 0; i < 32; ++i) {
        float4 v = p4[t + 256 * i];
        s += (v.x + v.y) + (v.z + v.w);
    }
#pragma unroll
    for (int off = 32; off; off >>= 1) s += __shfl_down(s, off, 64);

    __shared__ float ls[4];
    __shared__ int amlast;
    if ((t & 63) == 0) ls[t >> 6] = s;
    __syncthreads();
    if (t == 0) {
        part[bc * 2 + half] = (ls[0] + ls[1]) + (ls[2] + ls[3]);
        __threadfence();                      // release partial
        int old = atomicAdd(&cnt[b], 1);      // device-scope
        amlast = (old == 2 * C_ - 1);
    }
    __syncthreads();
    if (!amlast) return;

    // ---- last block for batch b: tiny GCN math, 256 threads ----
    __threadfence();                          // acquire all partials
    __shared__ float xn[C_], z1s[C_], hp[4][C_], wp[4][C_];
    int n = t & 63, q = t >> 6;
    if (t < C_) {
        float p0 = part[(b * C_ + t) * 2], p1 = part[(b * C_ + t) * 2 + 1];
        xn[t] = (p0 + p1) * (1.0f / (float)HW_);
    }
    __syncthreads();
    float hpart = 0.f;
#pragma unroll
    for (int i = 0; i < 16; ++i) {
        int cc = q * 16 + i;
        hpart += xn[cc] * g1_w[n * C_ + cc];
    }
    hp[q][n] = hpart;
    __syncthreads();
    if (t < C_) {
        float h = g1_b[t] + (hp[0][t] + hp[1][t]) + (hp[2][t] + hp[3][t]);
        z1s[t] = h * g2_w[0] + g2_b[0];
    }
    __syncthreads();
    float wpart = 0.f;
#pragma unroll
    for (int i = 0; i < 16; ++i) {
        int nn = q * 16 + i;
        wpart += z1s[nn] * theta_w[nn * C_ + n];
    }
    wp[q][n] = wpart;
    __syncthreads();
    if (t < C_) w_eff[b * C_ + t] = (wp[0][t] + wp[1][t]) + (wp[2][t] + wp[3][t]);
    if (t == 0) {
        float bb = 0.f;
#pragma unroll
        for (int nn = 0; nn < C_; ++nn) bb += z1s[nn] * theta_b[nn];
        bias_eff[b] = bb;
    }
}

// ---------------------------------------------------------------------------
// Kernel 2: fused y + phi + tanh, LDS-staged 64x128 tile, all-256-thread
// y-dot (2-way channel split). float4 loads/stores, nt stores.
//   y[p]        = bias_eff[b] + sum_c w_eff[b,c]*x[b,c,p]
//   out[b,c,p]  = fast_tanh(y[p]*phi_w[c] + phi_b[c] + x[b,c,p])
// grid = B * (HW/TILE) = 8192 blocks, 256 threads
// ---------------------------------------------------------------------------
__global__ __launch_bounds__(256) void k_fused_out(
    const float* __restrict__ x,
    const float* __restrict__ w_eff, const float* __restrict__ bias_eff,
    const float* __restrict__ phi_w, const float* __restrict__ phi_b,
    float* __restrict__ out) {
    __shared__ float tile[C_][TILE];   // 32 KiB
    __shared__ float ysp[2][TILE];
    __shared__ float wsh[C_], pw[C_], pb[C_];

    int t  = threadIdx.x;
    int b  = blockIdx.x >> 9;          // HW/TILE = 512 tiles per batch
    int ti = blockIdx.x & 511;
    int p0 = ti * TILE;

    if (t < C_) {
        wsh[t] = w_eff[b * C_ + t];
        pw[t]  = phi_w[t];
        pb[t]  = phi_b[t];
    }

    const float* xb = x + (size_t)b * C_ * HW_ + p0;
#pragma unroll
    for (int i = 0; i < 8; ++i) {
        int f = i * 256 + t;
        int c = f >> 5;                // TILE/4 = 32 float4 per channel row
        int j = f & 31;
        *(float4*)&tile[c][4 * j] =
            *(const float4*)(xb + (size_t)c * HW_ + 4 * j);
    }
    __syncthreads();

    {   // all 256 threads: pixel = t&127, channel-half h = t>>7
        int p = t & 127, h = t >> 7;
        float y = (h == 0) ? bias_eff[b] : 0.f;
#pragma unroll
        for (int i = 0; i < 32; ++i) y += wsh[h * 32 + i] * tile[h * 32 + i][p];
        ysp[h][p] = y;
    }
    __syncthreads();

    float* ob = out + (size_t)b * C_ * HW_ + p0;
#pragma unroll
    for (int i = 0; i < 8; ++i) {
        int f = i * 256 + t;
        int c = f >> 5;
        int j = f & 31;
        float4 v  = *(float4*)&tile[c][4 * j];
        float4 y0 = *(float4*)&ysp[0][4 * j];
        float4 y1 = *(float4*)&ysp[1][4 * j];
        float a = pw[c], d = pb[c];
        f4_t r;
        r.x = fast_tanh((y0.x + y1.x) * a + d + v.x);
        r.y = fast_tanh((y0.y + y1.y) * a + d + v.y);
        r.z = fast_tanh((y0.z + y1.z) * a + d + v.z);
        r.w = fast_tanh((y0.w + y1.w) * a + d + v.w);
        __builtin_nontemporal_store(r, (f4_t*)(ob + (size_t)c * HW_ + 4 * j));
    }
}

// ---------------------------------------------------------------------------
extern "C" void kernel_launch(void* const* d_in, const int* in_sizes, int n_in,
                              void* d_out, int out_size, void* d_ws, size_t ws_size,
                              hipStream_t stream) {
    const float* x       = (const float*)d_in[0];
    const float* theta_w = (const float*)d_in[1];
    const float* theta_b = (const float*)d_in[2];
    const float* g1_w    = (const float*)d_in[3];
    const float* g1_b    = (const float*)d_in[4];
    const float* g2_w    = (const float*)d_in[5];
    const float* g2_b    = (const float*)d_in[6];
    const float* phi_w   = (const float*)d_in[7];
    const float* phi_b   = (const float*)d_in[8];
    float* out = (float*)d_out;

    float* part     = (float*)d_ws;                 // B*C*2 floats
    float* w_eff    = part + B_ * C_ * 2;           // B*C floats
    float* bias_eff = w_eff + B_ * C_;              // B floats
    int*   cnt      = (int*)(bias_eff + B_);        // B ints

    hipMemsetAsync(cnt, 0, B_ * sizeof(int), stream);

    k_reduce_gcn<<<B_ * C_ * 2, 256, 0, stream>>>(
        x, theta_w, theta_b, g1_w, g1_b, g2_w, g2_b,
        part, w_eff, bias_eff, cnt);
    k_fused_out<<<B_ * (HW_ / TILE), 256, 0, stream>>>(
        x, w_eff, bias_eff, phi_w, phi_b, out);
}

// Round 8
// 137.515 us; speedup vs baseline: 5.2321x; 1.4636x over previous
//
#include <hip/hip_runtime.h>
#include <hip/hip_bf16.h>

// Problem constants (from reference setup_inputs)
#define B_   16
#define C_   64
#define HW_  65536   // 256*256

typedef float f2_t __attribute__((ext_vector_type(2)));

// fast branch-free tanh: 1 - 2/(e^2z + 1), clamped
__device__ __forceinline__ float fast_tanh(float z) {
    z = fminf(fmaxf(z, -15.f), 15.f);
    float e = __expf(2.f * z);
    return 1.f - 2.f * __builtin_amdgcn_rcpf(e + 1.f);
}

// ---------------------------------------------------------------------------
// Kernel 1: x_node[b,c] = mean over H*W of x[b,c,:,:]
// grid = B*C = 1024 blocks, 256 threads; float4 loads. NO fences, NO atomics.
// ---------------------------------------------------------------------------
__global__ __launch_bounds__(256) void k_reduce_mean(
    const float* __restrict__ x, float* __restrict__ x_node) {
    int bc  = blockIdx.x;                    // 0..1023  (b*64 + c)
    int tid = threadIdx.x;                   // 0..255
    const float4* p4 = (const float4*)(x + (size_t)bc * HW_);

    float s = 0.f;
#pragma unroll
    for (int i = 0; i < 64; ++i) {
        float4 v = p4[tid + 256 * i];
        s += (v.x + v.y) + (v.z + v.w);
    }
#pragma unroll
    for (int off = 32; off; off >>= 1) s += __shfl_down(s, off, 64);

    __shared__ float ls[4];
    int wid = tid >> 6, lane = tid & 63;
    if (lane == 0) ls[wid] = s;
    __syncthreads();
    if (tid == 0) {
        float t = (ls[0] + ls[1]) + (ls[2] + ls[3]);
        x_node[bc] = t * (1.0f / (float)HW_);
    }
}

// ---------------------------------------------------------------------------
// Kernel 2: tiny GCN math ->  w_eff[b,c], bias_eff[b]   (one block)
// ---------------------------------------------------------------------------
__global__ __launch_bounds__(1024) void k_small(
    const float* __restrict__ x_node,
    const float* __restrict__ theta_w, const float* __restrict__ theta_b,
    const float* __restrict__ g1_w,    const float* __restrict__ g1_b,
    const float* __restrict__ g2_w,    const float* __restrict__ g2_b,
    float* __restrict__ w_eff, float* __restrict__ bias_eff) {
    int t = threadIdx.x;
    int b = t >> 6, n = t & 63;

    __shared__ float z1s[B_][C_];
    float h = g1_b[n];
#pragma unroll
    for (int c = 0; c < C_; ++c) h += x_node[b * C_ + c] * g1_w[n * C_ + c];
    z1s[b][n] = h * g2_w[0] + g2_b[0];
    __syncthreads();

    int c = n;
    float w = 0.f;
#pragma unroll
    for (int nn = 0; nn < C_; ++nn) w += z1s[b][nn] * theta_w[nn * C_ + c];
    w_eff[b * C_ + c] = w;

    if (c == 0) {
        float bb = 0.f;
#pragma unroll
        for (int nn = 0; nn < C_; ++nn) bb += z1s[b][nn] * theta_b[nn];
        bias_eff[b] = bb;
    }
}

// ---------------------------------------------------------------------------
// Kernel 3: fused y + phi + tanh, REGISTER version -- no LDS, no barriers.
// Each thread: 2 consecutive pixels (float2), all 64 channels in registers
// (128 VGPRs). y accumulated during the load loop; 64 nt float2 stores.
//   y[p]        = bias_eff[b] + sum_c w_eff[b,c]*x[b,c,p]
//   out[b,c,p]  = fast_tanh(y[p]*phi_w[c] + phi_b[c] + x[b,c,p])
// Each block: 256 threads x 2 pixels = 512 pixels.
// grid = B * (HW/512) = 16 * 128 = 2048 blocks; 128 blocks per batch.
// ---------------------------------------------------------------------------
__global__ __launch_bounds__(256) void k_fused_reg(
    const float* __restrict__ x,
    const float* __restrict__ w_eff, const float* __restrict__ bias_eff,
    const float* __restrict__ phi_w, const float* __restrict__ phi_b,
    float* __restrict__ out) {
    int b    = blockIdx.x >> 7;                      // 128 blocks per batch
    int pix  = ((blockIdx.x & 127) * 256 + threadIdx.x) * 2;

    const float* xb = x + (size_t)b * C_ * HW_ + pix;
    const float* wb = w_eff + b * C_;                // uniform -> s_load

    f2_t xs[C_];
    float y0 = bias_eff[b];
    float y1 = y0;
#pragma unroll
    for (int c = 0; c < C_; ++c) {
        f2_t v = *(const f2_t*)(xb + (size_t)c * HW_);
        xs[c] = v;
        float w = wb[c];
        y0 += w * v.x;
        y1 += w * v.y;
    }

    float* ob = out + (size_t)b * C_ * HW_ + pix;
#pragma unroll
    for (int c = 0; c < C_; ++c) {
        float a = phi_w[c], d = phi_b[c];
        f2_t r;
        r.x = fast_tanh(y0 * a + d + xs[c].x);
        r.y = fast_tanh(y1 * a + d + xs[c].y);
        __builtin_nontemporal_store(r, (f2_t*)(ob + (size_t)c * HW_));
    }
}

// ---------------------------------------------------------------------------
extern "C" void kernel_launch(void* const* d_in, const int* in_sizes, int n_in,
                              void* d_out, int out_size, void* d_ws, size_t ws_size,
                              hipStream_t stream) {
    const float* x       = (const float*)d_in[0];
    const float* theta_w = (const float*)d_in[1];
    const float* theta_b = (const float*)d_in[2];
    const float* g1_w    = (const float*)d_in[3];
    const float* g1_b    = (const float*)d_in[4];
    const float* g2_w    = (const float*)d_in[5];
    const float* g2_b    = (const float*)d_in[6];
    const float* phi_w   = (const float*)d_in[7];
    const float* phi_b   = (const float*)d_in[8];
    float* out = (float*)d_out;

    float* x_node   = (float*)d_ws;                 // B*C floats
    float* w_eff    = x_node + B_ * C_;             // B*C floats
    float* bias_eff = w_eff + B_ * C_;              // B floats

    k_reduce_mean<<<B_ * C_, 256, 0, stream>>>(x, x_node);
    k_small<<<1, B_ * C_, 0, stream>>>(x_node, theta_w, theta_b, g1_w, g1_b,
                                       g2_w, g2_b, w_eff, bias_eff);
    k_fused_reg<<<B_ * (HW_ / 512), 256, 0, stream>>>(
        x, w_eff, bias_eff, phi_w, phi_b, out);
}

// Round 9
// 126.184 us; speedup vs baseline: 5.7020x; 1.0898x over previous
//
#include <hip/hip_runtime.h>
#include <hip/hip_bf16.h>

// Problem constants (from reference setup_inputs)
#define B_   16
#define C_   64
#define HW_  65536   // 256*256

typedef float f2_t __attribute__((ext_vector_type(2)));

// fast branch-free tanh: 1 - 2/(e^2z + 1), clamped
__device__ __forceinline__ float fast_tanh(float z) {
    z = fminf(fmaxf(z, -15.f), 15.f);
    float e = __expf(2.f * z);
    return 1.f - 2.f * __builtin_amdgcn_rcpf(e + 1.f);
}

// ---------------------------------------------------------------------------
// Kernel 1: x_node[b,c] = mean over H*W of x[b,c,:,:]
// grid = B*C = 1024 blocks, 256 threads; float4 loads. NO fences, NO atomics.
// Regular (allocating) loads on purpose: x should be L3-resident afterwards.
// ---------------------------------------------------------------------------
__global__ __launch_bounds__(256) void k_reduce_mean(
    const float* __restrict__ x, float* __restrict__ x_node) {
    int bc  = blockIdx.x;                    // 0..1023  (b*64 + c)
    int tid = threadIdx.x;                   // 0..255
    const float4* p4 = (const float4*)(x + (size_t)bc * HW_);

    float s = 0.f;
#pragma unroll
    for (int i = 0; i < 64; ++i) {
        float4 v = p4[tid + 256 * i];
        s += (v.x + v.y) + (v.z + v.w);
    }
#pragma unroll
    for (int off = 32; off; off >>= 1) s += __shfl_down(s, off, 64);

    __shared__ float ls[4];
    int wid = tid >> 6, lane = tid & 63;
    if (lane == 0) ls[wid] = s;
    __syncthreads();
    if (tid == 0) {
        float t = (ls[0] + ls[1]) + (ls[2] + ls[3]);
        x_node[bc] = t * (1.0f / (float)HW_);
    }
}

// ---------------------------------------------------------------------------
// Kernel 2: fused GCN-math + y + phi + tanh. Each block FIRST redundantly
// computes the tiny GCN math (deterministic, weights L2/L3-hot, ~4 barriers,
// negligible vs 512 pixels of memory traffic), THEN does the register-
// resident pixel pass: 2 consecutive pixels/thread, all 64 channels in
// registers, y accumulated during loads, 64 nt float2 stores.
// Pixel chunks are processed in REVERSE order so the first reads hit the
// L3 lines most recently touched by k_reduce_mean (LRU-freshest tail).
// grid = B * (HW/512) = 2048 blocks; 128 blocks per batch.
// ---------------------------------------------------------------------------
__global__ __launch_bounds__(256) void k_fused_reg(
    const float* __restrict__ x, const float* __restrict__ x_node,
    const float* __restrict__ theta_w, const float* __restrict__ theta_b,
    const float* __restrict__ g1_w,    const float* __restrict__ g1_b,
    const float* __restrict__ g2_w,    const float* __restrict__ g2_b,
    const float* __restrict__ phi_w,   const float* __restrict__ phi_b,
    float* __restrict__ out) {
    __shared__ float xn[C_], z1[C_], wsh[C_], pw[C_], pb[C_];
    __shared__ float hp[4][C_];
    __shared__ float bias_s;

    int t = threadIdx.x;
    int b = blockIdx.x >> 7;                 // 128 blocks per batch
    int chunk = 127 - (blockIdx.x & 127);    // REVERSED pixel order
    int pix = (chunk * 256 + t) * 2;

    // ---- per-block tiny GCN math (redundant, deterministic) ----
    int n = t & 63, q = t >> 6;
    if (t < C_) { xn[t] = x_node[b * C_ + t]; pw[t] = phi_w[t]; pb[t] = phi_b[t]; }
    __syncthreads();
    float hpart = 0.f;
#pragma unroll
    for (int i = 0; i < 16; ++i) {
        int c = q * 16 + i;
        hpart += xn[c] * g1_w[n * C_ + c];
    }
    hp[q][n] = hpart;
    __syncthreads();
    if (t < C_) {
        float h = g1_b[t] + (hp[0][t] + hp[1][t]) + (hp[2][t] + hp[3][t]);
        z1[t] = h * g2_w[0] + g2_b[0];
    }
    __syncthreads();
    float wpart = 0.f;
#pragma unroll
    for (int i = 0; i < 16; ++i) {
        int nn = q * 16 + i;
        wpart += z1[nn] * theta_w[nn * C_ + n];
    }
    hp[q][n] = wpart;                        // reuse hp
    if (t == 0) {
        float bb = 0.f;
#pragma unroll
        for (int nn = 0; nn < C_; ++nn) bb += z1[nn] * theta_b[nn];
        bias_s = bb;
    }
    __syncthreads();
    if (t < C_) wsh[t] = (hp[0][t] + hp[1][t]) + (hp[2][t] + hp[3][t]);
    __syncthreads();

    // ---- register-resident pixel pass ----
    const float* xb = x + (size_t)b * C_ * HW_ + pix;

    f2_t xs[C_];
    float y0 = bias_s;
    float y1 = y0;
#pragma unroll
    for (int c = 0; c < C_; ++c) {
        f2_t v = *(const f2_t*)(xb + (size_t)c * HW_);
        xs[c] = v;
        float w = wsh[c];
        y0 += w * v.x;
        y1 += w * v.y;
    }

    float* ob = out + (size_t)b * C_ * HW_ + pix;
#pragma unroll
    for (int c = 0; c < C_; ++c) {
        float a = pw[c], d = pb[c];
        f2_t r;
        r.x = fast_tanh(y0 * a + d + xs[c].x);
        r.y = fast_tanh(y1 * a + d + xs[c].y);
        __builtin_nontemporal_store(r, (f2_t*)(ob + (size_t)c * HW_));
    }
}

// ---------------------------------------------------------------------------
extern "C" void kernel_launch(void* const* d_in, const int* in_sizes, int n_in,
                              void* d_out, int out_size, void* d_ws, size_t ws_size,
                              hipStream_t stream) {
    const float* x       = (const float*)d_in[0];
    const float* theta_w = (const float*)d_in[1];
    const float* theta_b = (const float*)d_in[2];
    const float* g1_w    = (const float*)d_in[3];
    const float* g1_b    = (const float*)d_in[4];
    const float* g2_w    = (const float*)d_in[5];
    const float* g2_b    = (const float*)d_in[6];
    const float* phi_w   = (const float*)d_in[7];
    const float* phi_b   = (const float*)d_in[8];
    float* out = (float*)d_out;

    float* x_node = (float*)d_ws;            // B*C floats

    k_reduce_mean<<<B_ * C_, 256, 0, stream>>>(x, x_node);
    k_fused_reg<<<B_ * (HW_ / 512), 256, 0, stream>>>(
        x, x_node, theta_w, theta_b, g1_w, g1_b, g2_w, g2_b,
        phi_w, phi_b, out);
}